// Round 1
// baseline (2996.398 us; speedup 1.0000x reference)
//
#include <hip/hip_runtime.h>
#include <math.h>

#define B_ 16
#define W_ 512
#define H_ 512
#define S_ (W_*H_)          // 262144 elements per batch image
#define R_ 15               // maxpool radius (k=31)
#define ALPHA_ 0.15f
#define MU_ 10.0f
#define TAU_ 0.125f
#define SIG_ 0.125f
#define EPS_ 1e-6f
#define INV1PT_ (1.0f/(1.0f+TAU_))

// ---- order-preserving float <-> uint key ----
__device__ __forceinline__ unsigned int fkey(float f){
  unsigned int b = __float_as_uint(f);
  return (b & 0x80000000u) ? ~b : (b | 0x80000000u);
}
__device__ __forceinline__ float funkey(unsigned int k){
  unsigned int b = (k & 0x80000000u) ? (k & 0x7fffffffu) : ~k;
  return __uint_as_float(b);
}

// ---- K1: horizontal 31-tap max over R and max(G,B), one row per block ----
__global__ __launch_bounds__(256) void hmax_kernel(const float* __restrict__ Iy,
                                                   float* __restrict__ Rh,
                                                   float* __restrict__ GBh){
  __shared__ float sR[W_];
  __shared__ float sG[W_];
  int b = blockIdx.x >> 9;
  int i = blockIdx.x & 511;
  const float* row = Iy + (size_t)b*3*S_ + (size_t)i*W_;
  for (int t = threadIdx.x; t < W_; t += 256){
    sR[t] = row[t];
    sG[t] = fmaxf(row[S_ + t], row[2*S_ + t]);
  }
  __syncthreads();
  for (int t = threadIdx.x; t < W_; t += 256){
    int j0 = max(t - R_, 0), j1 = min(t + R_, W_-1);
    float mR = -1e30f, mG = -1e30f;
    for (int j = j0; j <= j1; ++j){
      mR = fmaxf(mR, sR[j]);
      mG = fmaxf(mG, sG[j]);
    }
    size_t o = (size_t)b*S_ + (size_t)i*W_ + t;
    Rh[o] = mR; GBh[o] = mG;
  }
}

// ---- K2: vertical 31-tap max + x = |Rmax - GBmax| + R ----
__global__ __launch_bounds__(256) void vmax_x_kernel(const float* __restrict__ Rh,
                                                     const float* __restrict__ GBh,
                                                     const float* __restrict__ Iy,
                                                     float* __restrict__ xo){
  int j = blockIdx.x*64 + threadIdx.x;
  int i = blockIdx.y*4 + threadIdx.y;
  int b = blockIdx.z;
  int i0 = max(i - R_, 0), i1 = min(i + R_, H_-1);
  size_t col = (size_t)b*S_ + j;
  float mR = -1e30f, mG = -1e30f;
  for (int r = i0; r <= i1; ++r){
    mR = fmaxf(mR, Rh[col + (size_t)r*W_]);
    mG = fmaxf(mG, GBh[col + (size_t)r*W_]);
  }
  float Rv = Iy[(size_t)b*3*S_ + (size_t)i*W_ + j];
  xo[(size_t)b*S_ + (size_t)i*W_ + j] = fabsf(mR - mG) + Rv;
}

// ---- K3/K6: exact k-th order statistic per batch via 4-pass radix select ----
// One block per (batch, rank). Wave-level match-any aggregation avoids the
// 64-way LDS-atomic serialization that uniform data would cause on pass 0.
__global__ __launch_bounds__(512) void select_kernel(const float* __restrict__ data,
                                                     float* __restrict__ out_vals,
                                                     int r0, int r1, int r2, int r3,
                                                     int nranks){
  __shared__ unsigned int hist[256];
  __shared__ unsigned int s_pref;
  __shared__ int s_k;
  int job = blockIdx.x;
  int b = job / nranks, ri = job - b*nranks;
  int rank = (ri==0) ? r0 : (ri==1) ? r1 : (ri==2) ? r2 : r3;
  const float* p = data + (size_t)b*S_;
  if (threadIdx.x == 0){ s_pref = 0u; s_k = rank; }
  for (int pass = 0; pass < 4; ++pass){
    int shift = 24 - 8*pass;
    unsigned int prefmask = (pass==0) ? 0u : (0xFFFFFFFFu << (shift+8));
    if (threadIdx.x < 256) hist[threadIdx.x] = 0u;
    __syncthreads();
    unsigned int pref = s_pref;
    for (int idx = threadIdx.x; idx < S_; idx += 512){
      unsigned int key = fkey(p[idx]);
      bool ok = ((key & prefmask) == pref);
      unsigned int id = ok ? ((key >> shift) & 255u) : 256u;
      unsigned long long m = ~0ull;
      #pragma unroll
      for (int bit = 0; bit < 9; ++bit){
        unsigned long long v = __ballot((id >> bit) & 1u);
        m &= ((id >> bit) & 1u) ? v : ~v;
      }
      int lane = (int)(threadIdx.x & 63u);
      int leader = __ffsll(m) - 1;
      if (ok && lane == leader) atomicAdd(&hist[id], (unsigned int)__popcll(m));
    }
    __syncthreads();
    if (threadIdx.x == 0){
      unsigned int c = 0; int k = s_k; unsigned int sel = 255u;
      for (int q = 0; q < 256; ++q){
        unsigned int h = hist[q];
        if ((unsigned int)k < c + h){ sel = (unsigned int)q; k -= (int)c; break; }
        c += h;
      }
      s_k = k;
      s_pref = pref | (sel << shift);
    }
    __syncthreads();
  }
  if (threadIdx.x == 0) out_vals[job] = funkey(s_pref);
}

// ---- K5: N_hat = clip((x-lo)/(hi-lo+eps),0,1)  +  grad_mag for median ----
__global__ __launch_bounds__(256) void nhat_gm_kernel(const float* __restrict__ x,
                                                      const float* __restrict__ vx,
                                                      float* __restrict__ nh,
                                                      float* __restrict__ gm){
  int j = blockIdx.x*64 + threadIdx.x;
  int i = blockIdx.y*4 + threadIdx.y;
  int b = blockIdx.z;
  // jnp.quantile linear interp: pos = q*(n-1); n=262144
  // p=0.01 -> 2621.43 ; p=0.99 -> 259521.57
  float lo = vx[b*4+0]*(1.0f-0.43f) + vx[b*4+1]*0.43f;
  float hi = vx[b*4+2]*(1.0f-0.57f) + vx[b*4+3]*0.57f;
  float inv = 1.0f/(hi - lo + EPS_);
  size_t base = (size_t)b*S_ + (size_t)i*W_ + j;
  float c = fminf(fmaxf((x[base] - lo)*inv, 0.f), 1.f);
  float dx = 0.f, dy = 0.f;
  if (j < W_-1) dx = fminf(fmaxf((x[base+1]  - lo)*inv, 0.f), 1.f) - c;
  if (i < H_-1) dy = fminf(fmaxf((x[base+W_] - lo)*inv, 0.f), 1.f) - c;
  nh[base] = c;
  gm[base] = sqrtf(dx*dx + dy*dy + EPS_);
}

// ---- K8: init PD state ----
__global__ __launch_bounds__(256) void init_kernel(const float* __restrict__ nh,
                                                   float* __restrict__ u,
                                                   float* __restrict__ ub,
                                                   float* __restrict__ px,
                                                   float* __restrict__ py){
  size_t idx = (size_t)blockIdx.x*256 + threadIdx.x;
  if (idx < (size_t)B_*S_){
    float v = nh[idx];
    u[idx] = v; ub[idx] = v; px[idx] = 0.f; py[idx] = 0.f;
  }
}

// ---- K9: one fused primal-dual iteration (all reads from OLD state) ----
// Weights aW = 0.15*(1+10*exp(-|grad N_hat|/sigma)) recomputed on the fly
// (memory-bound kernel; 4 hw-exp/pixel is cheaper than 32 MB/iter of reads).
__global__ __launch_bounds__(256) void pd_iter_kernel(const float* __restrict__ ub_in,
                                                      const float* __restrict__ px_in,
                                                      const float* __restrict__ py_in,
                                                      float* __restrict__ ub_out,
                                                      float* __restrict__ px_out,
                                                      float* __restrict__ py_out,
                                                      float* __restrict__ u,
                                                      const float* __restrict__ nh,
                                                      const float* __restrict__ vg){
  int j = blockIdx.x*64 + threadIdx.x;
  int i = blockIdx.y*4 + threadIdx.y;
  int b = blockIdx.z;
  float sig = fmaxf(0.5f*(vg[b*2] + vg[b*2+1]), EPS_);  // median, pos frac = 0.5
  float invs = 1.0f/sig;
  size_t base = (size_t)b*S_ + (size_t)i*W_ + j;

  float nhc = nh[base];
  float ub  = ub_in[base];

  // own px, py update
  float dxn = (j < W_-1) ? (nh[base+1]  - nhc) : 0.f;
  float dyn = (i < H_-1) ? (nh[base+W_] - nhc) : 0.f;
  float ax = ALPHA_*(1.0f + MU_*__expf(-fabsf(dxn)*invs));
  float ay = ALPHA_*(1.0f + MU_*__expf(-fabsf(dyn)*invs));
  float dx = (j < W_-1) ? (ub_in[base+1]  - ub) : 0.f;
  float dy = (i < H_-1) ? (ub_in[base+W_] - ub) : 0.f;
  float pxn = fminf(fmaxf(px_in[base] + SIG_*dx, -ax), ax);
  float pyn = fminf(fmaxf(py_in[base] + SIG_*dy, -ay), ay);
  px_out[base] = pxn;
  py_out[base] = pyn;

  // divergence needs freshly-updated left/up duals: recompute from old state
  float div = pxn + pyn;
  if (j > 0){
    float nhl = nh[base-1];
    float axl = ALPHA_*(1.0f + MU_*__expf(-fabsf(nhc - nhl)*invs));
    float pxl = fminf(fmaxf(px_in[base-1] + SIG_*(ub - ub_in[base-1]), -axl), axl);
    div -= pxl;
  }
  if (i > 0){
    float nhu = nh[base-W_];
    float ayu = ALPHA_*(1.0f + MU_*__expf(-fabsf(nhc - nhu)*invs));
    float pyu = fminf(fmaxf(py_in[base-W_] + SIG_*(ub - ub_in[base-W_]), -ayu), ayu);
    div -= pyu;
  }

  float uo = u[base];
  float un = (uo + TAU_*div + TAU_*nhc) * INV1PT_;
  u[base] = un;
  ub_out[base] = 2.0f*un - uo;
}

// ---- K10: final clip to output ----
__global__ __launch_bounds__(256) void final_kernel(const float* __restrict__ u,
                                                    float* __restrict__ out){
  size_t idx = (size_t)blockIdx.x*256 + threadIdx.x;
  if (idx < (size_t)B_*S_) out[idx] = fminf(fmaxf(u[idx], 0.f), 1.f);
}

extern "C" void kernel_launch(void* const* d_in, const int* in_sizes, int n_in,
                              void* d_out, int out_size, void* d_ws, size_t ws_size,
                              hipStream_t stream){
  const float* Iy = (const float*)d_in[0];
  float* out = (float*)d_out;
  char* ws = (char*)d_ws;
  const size_t SLOT = (size_t)B_*S_*sizeof(float);   // 16 MiB per field
  float* slot[8];
  for (int q = 0; q < 8; ++q) slot[q] = (float*)(ws + (size_t)q*SLOT);
  float* vx = (float*)(ws + (size_t)8*SLOT);          // 64 floats (lo/hi order stats)
  float* vg = vx + 64;                                // 32 floats (median order stats)

  // buffer lifetime reuse:
  // slot0: Rh -> gm -> py ping B
  // slot1: GBh -> ubar ping B
  // slot2: x   -> px ping B
  // slot3: N_hat (live whole run)
  // slot4: u
  // slot5: ubar ping A, slot6: px ping A, slot7: py ping A
  float* Rh  = slot[0];
  float* GBh = slot[1];
  float* xb  = slot[2];
  float* nh  = slot[3];
  float* u   = slot[4];
  float* ubar[2] = { slot[5], slot[1] };
  float* px[2]   = { slot[6], slot[2] };
  float* py[2]   = { slot[7], slot[0] };

  dim3 blk(64, 4, 1), grd(W_/64, H_/4, B_);

  hmax_kernel<<<B_*H_, 256, 0, stream>>>(Iy, Rh, GBh);
  vmax_x_kernel<<<grd, blk, 0, stream>>>(Rh, GBh, Iy, xb);
  // lo/hi order stats: ranks floor/ceil of 0.01*(N-1)=2621.43, 0.99*(N-1)=259521.57
  select_kernel<<<B_*4, 512, 0, stream>>>(xb, vx, 2621, 2622, 259521, 259522, 4);
  nhat_gm_kernel<<<grd, blk, 0, stream>>>(xb, vx, nh, Rh /* gm reuses slot0 */);
  // median order stats: ranks 131071, 131072 (pos = 131071.5)
  select_kernel<<<B_*2, 512, 0, stream>>>(Rh, vg, 131071, 131072, 0, 0, 2);

  int total = B_*S_;
  init_kernel<<<(total+255)/256, 256, 0, stream>>>(nh, u, ubar[0], px[0], py[0]);

  int cur = 0;
  for (int it = 0; it < 30; ++it){
    pd_iter_kernel<<<grd, blk, 0, stream>>>(ubar[cur], px[cur], py[cur],
                                            ubar[1-cur], px[1-cur], py[1-cur],
                                            u, nh, vg);
    cur ^= 1;
  }
  final_kernel<<<(total+255)/256, 256, 0, stream>>>(u, out);
}

// Round 2
// 1400.087 us; speedup vs baseline: 2.1402x; 2.1402x over previous
//
#include <hip/hip_runtime.h>
#include <math.h>

#define B_ 16
#define W_ 512
#define H_ 512
#define S_ (W_*H_)          // 262144 elements per batch image
#define R_ 15               // maxpool radius (k=31)
#define ALPHA_ 0.15f
#define MU_ 10.0f
#define TAU_ 0.125f
#define SIG_ 0.125f
#define EPS_ 1e-6f
#define INV1PT_ (1.0f/(1.0f+TAU_))

// ---- order-preserving float <-> uint key ----
__device__ __forceinline__ unsigned int fkey(float f){
  unsigned int b = __float_as_uint(f);
  return (b & 0x80000000u) ? ~b : (b | 0x80000000u);
}
__device__ __forceinline__ float funkey(unsigned int k){
  unsigned int b = (k & 0x80000000u) ? (k & 0x7fffffffu) : ~k;
  return __uint_as_float(b);
}

// ---- K1: horizontal 31-tap max over R and max(G,B), one row per block ----
__global__ __launch_bounds__(256) void hmax_kernel(const float* __restrict__ Iy,
                                                   float* __restrict__ Rh,
                                                   float* __restrict__ GBh){
  __shared__ float sR[W_];
  __shared__ float sG[W_];
  int b = blockIdx.x >> 9;
  int i = blockIdx.x & 511;
  const float* row = Iy + (size_t)b*3*S_ + (size_t)i*W_;
  for (int t = threadIdx.x; t < W_; t += 256){
    sR[t] = row[t];
    sG[t] = fmaxf(row[S_ + t], row[2*S_ + t]);
  }
  __syncthreads();
  for (int t = threadIdx.x; t < W_; t += 256){
    int j0 = max(t - R_, 0), j1 = min(t + R_, W_-1);
    float mR = -1e30f, mG = -1e30f;
    for (int j = j0; j <= j1; ++j){
      mR = fmaxf(mR, sR[j]);
      mG = fmaxf(mG, sG[j]);
    }
    size_t o = (size_t)b*S_ + (size_t)i*W_ + t;
    Rh[o] = mR; GBh[o] = mG;
  }
}

// ---- K2: vertical 31-tap max + x = |Rmax - GBmax| + R ----
__global__ __launch_bounds__(256) void vmax_x_kernel(const float* __restrict__ Rh,
                                                     const float* __restrict__ GBh,
                                                     const float* __restrict__ Iy,
                                                     float* __restrict__ xo){
  int j = blockIdx.x*64 + threadIdx.x;
  int i = blockIdx.y*4 + threadIdx.y;
  int b = blockIdx.z;
  int i0 = max(i - R_, 0), i1 = min(i + R_, H_-1);
  size_t col = (size_t)b*S_ + j;
  float mR = -1e30f, mG = -1e30f;
  for (int r = i0; r <= i1; ++r){
    mR = fmaxf(mR, Rh[col + (size_t)r*W_]);
    mG = fmaxf(mG, GBh[col + (size_t)r*W_]);
  }
  float Rv = Iy[(size_t)b*3*S_ + (size_t)i*W_ + j];
  xo[(size_t)b*S_ + (size_t)i*W_ + j] = fabsf(mR - mG) + Rv;
}

// ================= grid-parallel exact radix select =================
// Level 1: per-batch 4096-bin histogram of key[31:20] (LDS, merged via
// global atomics). Level 2: filtered histogram of key[19:8]. Level 3:
// filtered histogram of key[7:0]. Exact 32-bit order statistic.

__global__ __launch_bounds__(256) void hist12_kernel(const float* __restrict__ data,
                                                     unsigned int* __restrict__ hist,
                                                     int blocks_per_batch){
  __shared__ unsigned int h[4096];
  int b   = blockIdx.x / blocks_per_batch;
  int blk = blockIdx.x - b*blocks_per_batch;
  for (int t = threadIdx.x; t < 4096; t += 256) h[t] = 0u;
  __syncthreads();
  int chunk = S_ / blocks_per_batch;
  const float* p = data + (size_t)b*S_ + (size_t)blk*chunk;
  for (int idx = threadIdx.x; idx < chunk; idx += 256){
    unsigned int key = fkey(p[idx]);
    atomicAdd(&h[key >> 20], 1u);
  }
  __syncthreads();
  for (int t = threadIdx.x; t < 4096; t += 256)
    if (h[t]) atomicAdd(&hist[b*4096 + t], h[t]);
}

// filtered rescan: count keys with (key>>fshift)==pref into nbins buckets of
// (key>>bshift) & (nbins-1); per-job histogram.
__global__ __launch_bounds__(256) void hist_refine_kernel(const float* __restrict__ data,
                                                          const unsigned int* __restrict__ prefs,
                                                          unsigned int* __restrict__ hist,
                                                          int blocks_per_job, int nranks,
                                                          int fshift, int bshift, int nbins){
  __shared__ unsigned int h[4096];
  int job = blockIdx.x / blocks_per_job;
  int blk = blockIdx.x - job*blocks_per_job;
  int b = job / nranks;
  unsigned int pref = prefs[job];
  for (int t = threadIdx.x; t < nbins; t += 256) h[t] = 0u;
  __syncthreads();
  int chunk = S_ / blocks_per_job;
  const float* p = data + (size_t)b*S_ + (size_t)blk*chunk;
  for (int idx = threadIdx.x; idx < chunk; idx += 256){
    unsigned int key = fkey(p[idx]);
    if ((key >> fshift) == pref) atomicAdd(&h[(key >> bshift) & (unsigned)(nbins-1)], 1u);
  }
  __syncthreads();
  for (int t = threadIdx.x; t < nbins; t += 256)
    if (h[t]) atomicAdd(&hist[job*nbins + t], h[t]);
}

// pick bucket containing residual rank among 4096 bins.
// first=1: hist is per-batch, rank from args, pref := bin
// first=0: hist is per-job, rank from ranks[], pref := (pref<<12)|bin
__global__ __launch_bounds__(256) void pick12_kernel(const unsigned int* __restrict__ hist,
                                                     unsigned int* __restrict__ prefs,
                                                     int* __restrict__ ranks,
                                                     int r0, int r1, int r2, int r3,
                                                     int nranks, int first){
  __shared__ unsigned int part[256];
  __shared__ int s_owner, s_rem;
  int job = blockIdx.x;
  int b = job / nranks, ri = job - b*nranks;
  int rank; int base; unsigned int oldpref = 0u;
  if (first){
    rank = (ri==0) ? r0 : (ri==1) ? r1 : (ri==2) ? r2 : r3;
    base = b*4096;
  } else {
    rank = ranks[job];
    base = job*4096;
    oldpref = prefs[job];
  }
  int t = threadIdx.x;
  unsigned int local[16];
  unsigned int cnt = 0u;
  #pragma unroll
  for (int q = 0; q < 16; ++q){ local[q] = hist[base + t*16 + q]; cnt += local[q]; }
  part[t] = cnt;
  __syncthreads();
  if (t == 0){
    int rem = rank; int owner = 255;
    for (int q = 0; q < 256; ++q){
      if ((unsigned int)rem < part[q]){ owner = q; break; }
      rem -= (int)part[q];
    }
    s_owner = owner; s_rem = rem;
  }
  __syncthreads();
  if (t == s_owner){
    int rem = s_rem; unsigned int bin = (unsigned int)(t*16 + 15);
    #pragma unroll
    for (int q = 0; q < 16; ++q){
      if ((unsigned int)rem < local[q]){ bin = (unsigned int)(t*16 + q); break; }
      rem -= (int)local[q];
    }
    prefs[job] = first ? bin : ((oldpref << 12) | bin);
    ranks[job] = rem;
  }
}

// final 256-bin pick -> exact float value
__global__ __launch_bounds__(256) void pick3_kernel(const unsigned int* __restrict__ hist3,
                                                    const unsigned int* __restrict__ prefs,
                                                    const int* __restrict__ ranks,
                                                    float* __restrict__ outv,
                                                    int nranks){
  __shared__ unsigned int part[256];
  int job = blockIdx.x;
  part[threadIdx.x] = hist3[job*256 + threadIdx.x];
  __syncthreads();
  if (threadIdx.x == 0){
    int rem = ranks[job]; unsigned int bin = 255u;
    for (int q = 0; q < 256; ++q){
      if ((unsigned int)rem < part[q]){ bin = (unsigned int)q; break; }
      rem -= (int)part[q];
    }
    unsigned int key = (prefs[job] << 8) | bin;
    outv[job] = funkey(key);
  }
}

// ---- K5: N_hat = clip((x-lo)/(hi-lo+eps),0,1)  +  grad_mag for median ----
__global__ __launch_bounds__(256) void nhat_gm_kernel(const float* __restrict__ x,
                                                      const float* __restrict__ vx,
                                                      float* __restrict__ nh,
                                                      float* __restrict__ gm){
  int j = blockIdx.x*64 + threadIdx.x;
  int i = blockIdx.y*4 + threadIdx.y;
  int b = blockIdx.z;
  // jnp.quantile linear interp: pos = q*(n-1); n=262144
  // p=0.01 -> 2621.43 ; p=0.99 -> 259521.57
  float lo = vx[b*4+0]*(1.0f-0.43f) + vx[b*4+1]*0.43f;
  float hi = vx[b*4+2]*(1.0f-0.57f) + vx[b*4+3]*0.57f;
  float inv = 1.0f/(hi - lo + EPS_);
  size_t base = (size_t)b*S_ + (size_t)i*W_ + j;
  float c = fminf(fmaxf((x[base] - lo)*inv, 0.f), 1.f);
  float dx = 0.f, dy = 0.f;
  if (j < W_-1) dx = fminf(fmaxf((x[base+1]  - lo)*inv, 0.f), 1.f) - c;
  if (i < H_-1) dy = fminf(fmaxf((x[base+W_] - lo)*inv, 0.f), 1.f) - c;
  nh[base] = c;
  gm[base] = sqrtf(dx*dx + dy*dy + EPS_);
}

// ---- K8: init PD state ----
__global__ __launch_bounds__(256) void init_kernel(const float* __restrict__ nh,
                                                   float* __restrict__ u,
                                                   float* __restrict__ ub,
                                                   float* __restrict__ px,
                                                   float* __restrict__ py){
  size_t idx = (size_t)blockIdx.x*256 + threadIdx.x;
  if (idx < (size_t)B_*S_){
    float v = nh[idx];
    u[idx] = v; ub[idx] = v; px[idx] = 0.f; py[idx] = 0.f;
  }
}

// ---- K9: one fused primal-dual iteration (all reads from OLD state) ----
__global__ __launch_bounds__(256) void pd_iter_kernel(const float* __restrict__ ub_in,
                                                      const float* __restrict__ px_in,
                                                      const float* __restrict__ py_in,
                                                      float* __restrict__ ub_out,
                                                      float* __restrict__ px_out,
                                                      float* __restrict__ py_out,
                                                      float* __restrict__ u,
                                                      const float* __restrict__ nh,
                                                      const float* __restrict__ vg){
  int j = blockIdx.x*64 + threadIdx.x;
  int i = blockIdx.y*4 + threadIdx.y;
  int b = blockIdx.z;
  float sig = fmaxf(0.5f*(vg[b*2] + vg[b*2+1]), EPS_);  // median, pos frac = 0.5
  float invs = 1.0f/sig;
  size_t base = (size_t)b*S_ + (size_t)i*W_ + j;

  float nhc = nh[base];
  float ub  = ub_in[base];

  // own px, py update
  float dxn = (j < W_-1) ? (nh[base+1]  - nhc) : 0.f;
  float dyn = (i < H_-1) ? (nh[base+W_] - nhc) : 0.f;
  float ax = ALPHA_*(1.0f + MU_*__expf(-fabsf(dxn)*invs));
  float ay = ALPHA_*(1.0f + MU_*__expf(-fabsf(dyn)*invs));
  float dx = (j < W_-1) ? (ub_in[base+1]  - ub) : 0.f;
  float dy = (i < H_-1) ? (ub_in[base+W_] - ub) : 0.f;
  float pxn = fminf(fmaxf(px_in[base] + SIG_*dx, -ax), ax);
  float pyn = fminf(fmaxf(py_in[base] + SIG_*dy, -ay), ay);
  px_out[base] = pxn;
  py_out[base] = pyn;

  // divergence needs freshly-updated left/up duals: recompute from old state
  float div = pxn + pyn;
  if (j > 0){
    float nhl = nh[base-1];
    float axl = ALPHA_*(1.0f + MU_*__expf(-fabsf(nhc - nhl)*invs));
    float pxl = fminf(fmaxf(px_in[base-1] + SIG_*(ub - ub_in[base-1]), -axl), axl);
    div -= pxl;
  }
  if (i > 0){
    float nhu = nh[base-W_];
    float ayu = ALPHA_*(1.0f + MU_*__expf(-fabsf(nhc - nhu)*invs));
    float pyu = fminf(fmaxf(py_in[base-W_] + SIG_*(ub - ub_in[base-W_]), -ayu), ayu);
    div -= pyu;
  }

  float uo = u[base];
  float un = (uo + TAU_*div + TAU_*nhc) * INV1PT_;
  u[base] = un;
  ub_out[base] = 2.0f*un - uo;
}

// ---- K10: final clip to output ----
__global__ __launch_bounds__(256) void final_kernel(const float* __restrict__ u,
                                                    float* __restrict__ out){
  size_t idx = (size_t)blockIdx.x*256 + threadIdx.x;
  if (idx < (size_t)B_*S_) out[idx] = fminf(fmaxf(u[idx], 0.f), 1.f);
}

// select driver: exact k-th order stats for up to 4 ranks per batch
static void run_select(const float* data, float* outv,
                       int r0, int r1, int r2, int r3, int nranks,
                       unsigned int* hist1, unsigned int* hist2, unsigned int* hist3,
                       unsigned int* prefs, int* ranks, hipStream_t stream){
  int jobs = B_ * nranks;
  hipMemsetAsync(hist1, 0, (size_t)B_*4096*sizeof(unsigned int), stream);
  hist12_kernel<<<B_*16, 256, 0, stream>>>(data, hist1, 16);
  pick12_kernel<<<jobs, 256, 0, stream>>>(hist1, prefs, ranks, r0, r1, r2, r3, nranks, 1);
  hipMemsetAsync(hist2, 0, (size_t)jobs*4096*sizeof(unsigned int), stream);
  hist_refine_kernel<<<jobs*8, 256, 0, stream>>>(data, prefs, hist2, 8, nranks, 20, 8, 4096);
  pick12_kernel<<<jobs, 256, 0, stream>>>(hist2, prefs, ranks, 0, 0, 0, 0, nranks, 0);
  hipMemsetAsync(hist3, 0, (size_t)jobs*256*sizeof(unsigned int), stream);
  hist_refine_kernel<<<jobs*8, 256, 0, stream>>>(data, prefs, hist3, 8, nranks, 8, 0, 256);
  pick3_kernel<<<jobs, 256, 0, stream>>>(hist3, prefs, ranks, outv, nranks);
}

extern "C" void kernel_launch(void* const* d_in, const int* in_sizes, int n_in,
                              void* d_out, int out_size, void* d_ws, size_t ws_size,
                              hipStream_t stream){
  const float* Iy = (const float*)d_in[0];
  float* out = (float*)d_out;
  char* ws = (char*)d_ws;
  const size_t SLOT = (size_t)B_*S_*sizeof(float);   // 16 MiB per field
  float* slot[8];
  for (int q = 0; q < 8; ++q) slot[q] = (float*)(ws + (size_t)q*SLOT);
  float* vx = (float*)(ws + (size_t)8*SLOT);          // 64 floats (lo/hi order stats)
  float* vg = vx + 64;                                // 32 floats (median order stats)

  // buffer lifetime reuse:
  // slot0: Rh -> gm -> py ping B
  // slot1: GBh -> ubar ping B
  // slot2: x   -> px ping B
  // slot3: N_hat (live whole run)
  // slot4: select histograms (dead after selects) -> u
  // slot5: ubar ping A, slot6: px ping A, slot7: py ping A
  float* Rh  = slot[0];
  float* GBh = slot[1];
  float* xb  = slot[2];
  float* nh  = slot[3];
  float* u   = slot[4];
  float* ubar[2] = { slot[5], slot[1] };
  float* px[2]   = { slot[6], slot[2] };
  float* py[2]   = { slot[7], slot[0] };

  // select scratch inside slot4 (u not live until init_kernel)
  unsigned int* hist1 = (unsigned int*)(ws + (size_t)4*SLOT);                 // 256 KiB
  unsigned int* hist2 = (unsigned int*)(ws + (size_t)4*SLOT + (1u<<20));     // 1 MiB
  unsigned int* hist3 = (unsigned int*)(ws + (size_t)4*SLOT + (3u<<20));     // 64 KiB
  unsigned int* prefs = (unsigned int*)(ws + (size_t)4*SLOT + (4u<<20));     // 64 u32
  int*          ranks = (int*)(prefs + 64);                                  // 64 i32

  dim3 blk(64, 4, 1), grd(W_/64, H_/4, B_);

  hmax_kernel<<<B_*H_, 256, 0, stream>>>(Iy, Rh, GBh);
  vmax_x_kernel<<<grd, blk, 0, stream>>>(Rh, GBh, Iy, xb);
  // lo/hi order stats: ranks floor/ceil of 0.01*(N-1)=2621.43, 0.99*(N-1)=259521.57
  run_select(xb, vx, 2621, 2622, 259521, 259522, 4, hist1, hist2, hist3, prefs, ranks, stream);
  nhat_gm_kernel<<<grd, blk, 0, stream>>>(xb, vx, nh, Rh /* gm reuses slot0 */);
  // median order stats: ranks 131071, 131072 (pos = 131071.5)
  run_select(Rh, vg, 131071, 131072, 0, 0, 2, hist1, hist2, hist3, prefs, ranks, stream);

  int total = B_*S_;
  init_kernel<<<(total+255)/256, 256, 0, stream>>>(nh, u, ubar[0], px[0], py[0]);

  int cur = 0;
  for (int it = 0; it < 30; ++it){
    pd_iter_kernel<<<grd, blk, 0, stream>>>(ubar[cur], px[cur], py[cur],
                                            ubar[1-cur], px[1-cur], py[1-cur],
                                            u, nh, vg);
    cur ^= 1;
  }
  final_kernel<<<(total+255)/256, 256, 0, stream>>>(u, out);
}

// Round 3
// 872.602 us; speedup vs baseline: 3.4339x; 1.6045x over previous
//
#include <hip/hip_runtime.h>
#include <math.h>

#define B_ 16
#define W_ 512
#define H_ 512
#define S_ (W_*H_)          // 262144 elements per batch image
#define R_ 15               // maxpool radius (k=31)
#define ALPHA_ 0.15f
#define MU_ 10.0f
#define TAU_ 0.125f
#define SIG_ 0.125f
#define EPS_ 1e-6f
#define INV1PT_ (1.0f/(1.0f+TAU_))

// ---- order-preserving float <-> uint key ----
__device__ __forceinline__ unsigned int fkey(float f){
  unsigned int b = __float_as_uint(f);
  return (b & 0x80000000u) ? ~b : (b | 0x80000000u);
}
__device__ __forceinline__ float funkey(unsigned int k){
  unsigned int b = (k & 0x80000000u) ? (k & 0x7fffffffu) : ~k;
  return __uint_as_float(b);
}

// ---- K1: horizontal 31-tap max over R and max(G,B), one row per block ----
__global__ __launch_bounds__(256) void hmax_kernel(const float* __restrict__ Iy,
                                                   float* __restrict__ Rh,
                                                   float* __restrict__ GBh){
  __shared__ float sR[W_];
  __shared__ float sG[W_];
  int b = blockIdx.x >> 9;
  int i = blockIdx.x & 511;
  const float* row = Iy + (size_t)b*3*S_ + (size_t)i*W_;
  for (int t = threadIdx.x; t < W_; t += 256){
    sR[t] = row[t];
    sG[t] = fmaxf(row[S_ + t], row[2*S_ + t]);
  }
  __syncthreads();
  for (int t = threadIdx.x; t < W_; t += 256){
    int j0 = max(t - R_, 0), j1 = min(t + R_, W_-1);
    float mR = -1e30f, mG = -1e30f;
    for (int j = j0; j <= j1; ++j){
      mR = fmaxf(mR, sR[j]);
      mG = fmaxf(mG, sG[j]);
    }
    size_t o = (size_t)b*S_ + (size_t)i*W_ + t;
    Rh[o] = mR; GBh[o] = mG;
  }
}

// ---- vertical 31-tap max via van Herk-Gil-Werman (segments of 31) ----
// Pass 1 (fwd): R[i] = running max restarting at i%31==0.
// Columns split into 9 chunks (8x62 + 1x16 rows), all 31-aligned.
__global__ __launch_bounds__(256) void vscan_fwd_kernel(const float* __restrict__ Rh,
                                                        const float* __restrict__ GBh,
                                                        float* __restrict__ Rf,
                                                        float* __restrict__ Gf){
  int gid = blockIdx.x*256 + threadIdx.x;   // 73728 threads
  int col = gid & 8191;                     // 16*512 columns
  int c   = gid >> 13;                      // chunk 0..8
  int b = col >> 9, j = col & 511;
  int i0 = c*62, i1 = (c==8) ? 512 : i0+62; // i0 % 31 == 0 always
  size_t base = (size_t)b*S_ + j;
  float rR = -1e30f, rG = -1e30f;
  int m = 0;
  for (int i = i0; i < i1; ++i){
    size_t o = base + (size_t)i*W_;
    float vR = Rh[o], vG = GBh[o];
    if (m == 0){ rR = vR; rG = vG; }
    else       { rR = fmaxf(rR, vR); rG = fmaxf(rG, vG); }
    Rf[o] = rR; Gf[o] = rG;
    m = (m==30) ? 0 : m+1;
  }
}

// Pass 2 (bwd): L[i] = running max restarting at i%31==30; combine:
// out[o] = max(L[o-15], R[min(o+15,511)]) for o>=15, else R[o+15];
// fused with x = |Rmax - GBmax| + R.
__global__ __launch_bounds__(256) void vscan_bwd_kernel(const float* __restrict__ Rh,
                                                        const float* __restrict__ GBh,
                                                        const float* __restrict__ Rf,
                                                        const float* __restrict__ Gf,
                                                        const float* __restrict__ Iy,
                                                        float* __restrict__ xo){
  int gid = blockIdx.x*256 + threadIdx.x;
  int col = gid & 8191;
  int c   = gid >> 13;
  int b = col >> 9, j = col & 511;
  int i0 = c*62, i1 = (c==8) ? 512 : i0+62;
  size_t base = (size_t)b*S_ + j;
  const float* IyR = Iy + (size_t)b*3*S_ + j;
  float lR = -1e30f, lG = -1e30f;
  int m = (c==8) ? 15 : 30;
  for (int i = i1-1; i >= i0; --i){
    size_t o64 = base + (size_t)i*W_;
    float vR = Rh[o64], vG = GBh[o64];
    if (m == 30){ lR = vR; lG = vG; }
    else        { lR = fmaxf(lR, vR); lG = fmaxf(lG, vG); }
    int o = i + 15;
    if (o < 512){
      int bi = min(i + 30, 511);
      size_t ob = base + (size_t)bi*W_;
      float mR = fmaxf(lR, Rf[ob]);
      float mG = fmaxf(lG, Gf[ob]);
      xo[base + (size_t)o*W_] = fabsf(mR - mG) + IyR[(size_t)o*W_];
    }
    m = (m==0) ? 30 : m-1;
  }
  if (c == 0){
    for (int o = 0; o < 15; ++o){
      size_t ob = base + (size_t)(o+15)*W_;
      float mR = Rf[ob], mG = Gf[ob];
      xo[base + (size_t)o*W_] = fabsf(mR - mG) + IyR[(size_t)o*W_];
    }
  }
}

// ================= grid-parallel exact radix select =================
__global__ __launch_bounds__(256) void hist12_kernel(const float* __restrict__ data,
                                                     unsigned int* __restrict__ hist,
                                                     int blocks_per_batch){
  __shared__ unsigned int h[4096];
  int b   = blockIdx.x / blocks_per_batch;
  int blk = blockIdx.x - b*blocks_per_batch;
  for (int t = threadIdx.x; t < 4096; t += 256) h[t] = 0u;
  __syncthreads();
  int chunk = S_ / blocks_per_batch;
  const float* p = data + (size_t)b*S_ + (size_t)blk*chunk;
  for (int idx = threadIdx.x; idx < chunk; idx += 256){
    unsigned int key = fkey(p[idx]);
    atomicAdd(&h[key >> 20], 1u);
  }
  __syncthreads();
  for (int t = threadIdx.x; t < 4096; t += 256)
    if (h[t]) atomicAdd(&hist[b*4096 + t], h[t]);
}

__global__ __launch_bounds__(256) void hist_refine_kernel(const float* __restrict__ data,
                                                          const unsigned int* __restrict__ prefs,
                                                          unsigned int* __restrict__ hist,
                                                          int blocks_per_job, int nranks,
                                                          int fshift, int bshift, int nbins){
  __shared__ unsigned int h[4096];
  int job = blockIdx.x / blocks_per_job;
  int blk = blockIdx.x - job*blocks_per_job;
  int b = job / nranks;
  unsigned int pref = prefs[job];
  for (int t = threadIdx.x; t < nbins; t += 256) h[t] = 0u;
  __syncthreads();
  int chunk = S_ / blocks_per_job;
  const float* p = data + (size_t)b*S_ + (size_t)blk*chunk;
  for (int idx = threadIdx.x; idx < chunk; idx += 256){
    unsigned int key = fkey(p[idx]);
    if ((key >> fshift) == pref) atomicAdd(&h[(key >> bshift) & (unsigned)(nbins-1)], 1u);
  }
  __syncthreads();
  for (int t = threadIdx.x; t < nbins; t += 256)
    if (h[t]) atomicAdd(&hist[job*nbins + t], h[t]);
}

__global__ __launch_bounds__(256) void pick12_kernel(const unsigned int* __restrict__ hist,
                                                     unsigned int* __restrict__ prefs,
                                                     int* __restrict__ ranks,
                                                     int r0, int r1, int r2, int r3,
                                                     int nranks, int first){
  __shared__ unsigned int part[256];
  __shared__ int s_owner, s_rem;
  int job = blockIdx.x;
  int b = job / nranks, ri = job - b*nranks;
  int rank; int base; unsigned int oldpref = 0u;
  if (first){
    rank = (ri==0) ? r0 : (ri==1) ? r1 : (ri==2) ? r2 : r3;
    base = b*4096;
  } else {
    rank = ranks[job];
    base = job*4096;
    oldpref = prefs[job];
  }
  int t = threadIdx.x;
  unsigned int local[16];
  unsigned int cnt = 0u;
  #pragma unroll
  for (int q = 0; q < 16; ++q){ local[q] = hist[base + t*16 + q]; cnt += local[q]; }
  part[t] = cnt;
  __syncthreads();
  if (t == 0){
    int rem = rank; int owner = 255;
    for (int q = 0; q < 256; ++q){
      if ((unsigned int)rem < part[q]){ owner = q; break; }
      rem -= (int)part[q];
    }
    s_owner = owner; s_rem = rem;
  }
  __syncthreads();
  if (t == s_owner){
    int rem = s_rem; unsigned int bin = (unsigned int)(t*16 + 15);
    #pragma unroll
    for (int q = 0; q < 16; ++q){
      if ((unsigned int)rem < local[q]){ bin = (unsigned int)(t*16 + q); break; }
      rem -= (int)local[q];
    }
    prefs[job] = first ? bin : ((oldpref << 12) | bin);
    ranks[job] = rem;
  }
}

__global__ __launch_bounds__(256) void pick3_kernel(const unsigned int* __restrict__ hist3,
                                                    const unsigned int* __restrict__ prefs,
                                                    const int* __restrict__ ranks,
                                                    float* __restrict__ outv,
                                                    int nranks){
  __shared__ unsigned int part[256];
  int job = blockIdx.x;
  part[threadIdx.x] = hist3[job*256 + threadIdx.x];
  __syncthreads();
  if (threadIdx.x == 0){
    int rem = ranks[job]; unsigned int bin = 255u;
    for (int q = 0; q < 256; ++q){
      if ((unsigned int)rem < part[q]){ bin = (unsigned int)q; break; }
      rem -= (int)part[q];
    }
    unsigned int key = (prefs[job] << 8) | bin;
    outv[job] = funkey(key);
  }
}

// ---- N_hat + grad_mag ----
__global__ __launch_bounds__(256) void nhat_gm_kernel(const float* __restrict__ x,
                                                      const float* __restrict__ vx,
                                                      float* __restrict__ nh,
                                                      float* __restrict__ gm){
  int j = blockIdx.x*64 + threadIdx.x;
  int i = blockIdx.y*4 + threadIdx.y;
  int b = blockIdx.z;
  float lo = vx[b*4+0]*(1.0f-0.43f) + vx[b*4+1]*0.43f;
  float hi = vx[b*4+2]*(1.0f-0.57f) + vx[b*4+3]*0.57f;
  float inv = 1.0f/(hi - lo + EPS_);
  size_t base = (size_t)b*S_ + (size_t)i*W_ + j;
  float c = fminf(fmaxf((x[base] - lo)*inv, 0.f), 1.f);
  float dx = 0.f, dy = 0.f;
  if (j < W_-1) dx = fminf(fmaxf((x[base+1]  - lo)*inv, 0.f), 1.f) - c;
  if (i < H_-1) dy = fminf(fmaxf((x[base+W_] - lo)*inv, 0.f), 1.f) - c;
  nh[base] = c;
  gm[base] = sqrtf(dx*dx + dy*dy + EPS_);
}

// ---- init PD state ----
__global__ __launch_bounds__(256) void init_kernel(const float* __restrict__ nh,
                                                   float* __restrict__ u,
                                                   float* __restrict__ ub,
                                                   float* __restrict__ px,
                                                   float* __restrict__ py){
  size_t idx = (size_t)blockIdx.x*256 + threadIdx.x;
  if (idx < (size_t)B_*S_){
    float v = nh[idx];
    u[idx] = v; ub[idx] = v; px[idx] = 0.f; py[idx] = 0.f;
  }
}

// ---- fused T-iteration primal-dual kernel ----
// Core 32x32, halo 8 (tile 48x48): core is bit-exact after <=8 iterations
// (dependency radius 1/iter). State ub/px/py staged in LDS; u, px, py, ub
// mirrors + clamp bounds ax/ay live in registers (9 px/thread).
#define CORE 32
#define HALO 8
#define TILE 48
#define NPIX (TILE*TILE)   // 2304
#define PPT 9              // NPIX / 256

__global__ __launch_bounds__(256, 4) void pd_fused_kernel(
    const float* __restrict__ u_in,  const float* __restrict__ ub_in,
    const float* __restrict__ px_in, const float* __restrict__ py_in,
    float* __restrict__ u_out,  float* __restrict__ ub_out,
    float* __restrict__ px_out, float* __restrict__ py_out,
    const float* __restrict__ nh_g, const float* __restrict__ vg, int T)
{
  __shared__ float ubS[NPIX], pxS[NPIX], pyS[NPIX], nhS[NPIX];
  int t = threadIdx.x;
  int jt = blockIdx.x, it = blockIdx.y, b = blockIdx.z;
  int gi0 = it*CORE - HALO, gj0 = jt*CORE - HALO;
  float sig = fmaxf(0.5f*(vg[2*b] + vg[2*b+1]), EPS_);
  float invs = 1.0f/sig;

  int   flags[PPT];
  float u_r[PPT], ub_r[PPT], px_r[PPT], py_r[PPT], ax[PPT], ay[PPT];

  #pragma unroll
  for (int k = 0; k < PPT; ++k){
    int p = t + k*256;
    int li = p / TILE, lj = p - li*TILE;
    int gi = gi0 + li, gj = gj0 + lj;
    int gic = min(max(gi, 0), H_-1), gjc = min(max(gj, 0), W_-1);
    size_t g = (size_t)b*S_ + (size_t)gic*W_ + gjc;
    int f = 0;
    if (gj > 0)      f |= 1;      // has left in image
    if (gj < W_-1)   f |= 2;      // has right in image
    if (gi > 0)      f |= 4;      // has up in image
    if (gi < H_-1)   f |= 8;      // has down in image
    if (lj < TILE-1) f |= 16;     // right neighbor inside tile
    if (li < TILE-1) f |= 32;     // down inside tile
    if (lj > 0)      f |= 64;     // left inside tile
    if (li > 0)      f |= 128;    // up inside tile
    if (li >= HALO && li < HALO+CORE && lj >= HALO && lj < HALO+CORE) f |= 256;
    flags[k] = f;
    u_r[k]  = u_in[g];
    ub_r[k] = ub_in[g];
    px_r[k] = px_in[g];
    py_r[k] = py_in[g];
    nhS[p] = nh_g[g];
    ubS[p] = ub_r[k];
    pxS[p] = px_r[k];
    pyS[p] = py_r[k];
  }
  __syncthreads();
  // precompute clamp bounds from N_hat gradients (iteration-invariant)
  #pragma unroll
  for (int k = 0; k < PPT; ++k){
    int p = t + k*256, f = flags[k];
    float nhc = nhS[p];
    int iR = p + ((f>>4)&1);
    int iD = p + TILE*((f>>5)&1);
    float dxn = (f&2) ? (nhS[iR] - nhc) : 0.f;
    float dyn = (f&8) ? (nhS[iD] - nhc) : 0.f;
    ax[k] = ALPHA_*(1.0f + MU_*__expf(-fabsf(dxn)*invs));
    ay[k] = ALPHA_*(1.0f + MU_*__expf(-fabsf(dyn)*invs));
  }
  for (int s = 0; s < T; ++s){
    __syncthreads();   // ubS writes (prev iter / entry) -> reads
    #pragma unroll
    for (int k = 0; k < PPT; ++k){
      int p = t + k*256, f = flags[k];
      int iR = p + ((f>>4)&1);
      int iD = p + TILE*((f>>5)&1);
      float dx = (f&2) ? (ubS[iR] - ub_r[k]) : 0.f;
      float dy = (f&8) ? (ubS[iD] - ub_r[k]) : 0.f;
      px_r[k] = fminf(fmaxf(px_r[k] + SIG_*dx, -ax[k]), ax[k]);
      py_r[k] = fminf(fmaxf(py_r[k] + SIG_*dy, -ay[k]), ay[k]);
      pxS[p] = px_r[k];
      pyS[p] = py_r[k];
    }
    __syncthreads();   // pxS/pyS writes -> reads
    #pragma unroll
    for (int k = 0; k < PPT; ++k){
      int p = t + k*256, f = flags[k];
      int iL = p - ((f>>6)&1);
      int iU = p - TILE*((f>>7)&1);
      float div = px_r[k] + py_r[k];
      if (f&1) div -= pxS[iL];
      if (f&4) div -= pyS[iU];
      float un = (u_r[k] + TAU_*div + TAU_*nhS[p]) * INV1PT_;
      ub_r[k] = 2.0f*un - u_r[k];
      u_r[k]  = un;
      ubS[p]  = ub_r[k];
    }
  }
  // write back core pixels only
  #pragma unroll
  for (int k = 0; k < PPT; ++k){
    if (flags[k] & 256){
      int p = t + k*256;
      int li = p / TILE, lj = p - li*TILE;
      size_t g = (size_t)b*S_ + (size_t)(gi0+li)*W_ + (gj0+lj);
      u_out[g]  = u_r[k];
      ub_out[g] = ub_r[k];
      px_out[g] = px_r[k];
      py_out[g] = py_r[k];
    }
  }
}

// ---- final clip ----
__global__ __launch_bounds__(256) void final_kernel(const float* __restrict__ u,
                                                    float* __restrict__ out){
  size_t idx = (size_t)blockIdx.x*256 + threadIdx.x;
  if (idx < (size_t)B_*S_) out[idx] = fminf(fmaxf(u[idx], 0.f), 1.f);
}

static void run_select(const float* data, float* outv,
                       int r0, int r1, int r2, int r3, int nranks,
                       unsigned int* hist1, unsigned int* hist2, unsigned int* hist3,
                       unsigned int* prefs, int* ranks, hipStream_t stream){
  int jobs = B_ * nranks;
  hipMemsetAsync(hist1, 0, (size_t)B_*4096*sizeof(unsigned int), stream);
  hist12_kernel<<<B_*16, 256, 0, stream>>>(data, hist1, 16);
  pick12_kernel<<<jobs, 256, 0, stream>>>(hist1, prefs, ranks, r0, r1, r2, r3, nranks, 1);
  hipMemsetAsync(hist2, 0, (size_t)jobs*4096*sizeof(unsigned int), stream);
  hist_refine_kernel<<<jobs*8, 256, 0, stream>>>(data, prefs, hist2, 8, nranks, 20, 8, 4096);
  pick12_kernel<<<jobs, 256, 0, stream>>>(hist2, prefs, ranks, 0, 0, 0, 0, nranks, 0);
  hipMemsetAsync(hist3, 0, (size_t)jobs*256*sizeof(unsigned int), stream);
  hist_refine_kernel<<<jobs*8, 256, 0, stream>>>(data, prefs, hist3, 8, nranks, 8, 0, 256);
  pick3_kernel<<<jobs, 256, 0, stream>>>(hist3, prefs, ranks, outv, nranks);
}

extern "C" void kernel_launch(void* const* d_in, const int* in_sizes, int n_in,
                              void* d_out, int out_size, void* d_ws, size_t ws_size,
                              hipStream_t stream){
  const float* Iy = (const float*)d_in[0];
  float* out = (float*)d_out;
  char* ws = (char*)d_ws;
  const size_t SLOT = (size_t)B_*S_*sizeof(float);   // 16 MiB per field
  float* slot[8];
  for (int q = 0; q < 8; ++q) slot[q] = (float*)(ws + (size_t)q*SLOT);
  float* vx = (float*)(ws + (size_t)8*SLOT);          // 64 floats
  float* vg = vx + 64;                                // 32 floats

  // Slot lifetimes:
  // s0: Rh -> gm -> py ping B        s1: GBh -> u ping A
  // s2: x -> ub ping A               s3: px ping A
  // s4: select hists -> py ping A    s5: Rf -> u ping B
  // s6: Gf -> ub ping B              s7: px ping B
  // nh lives in d_out (overwritten by final_kernel at the end).
  float* Rh  = slot[0];
  float* GBh = slot[1];
  float* Rf  = slot[5];
  float* Gf  = slot[6];
  float* xb  = slot[2];
  float* nh  = out;                 // d_out as scratch for N_hat
  float* uu[2]   = { slot[1], slot[5] };
  float* ubb[2]  = { slot[2], slot[6] };
  float* pxx[2]  = { slot[3], slot[7] };
  float* pyy[2]  = { slot[4], slot[0] };

  unsigned int* hist1 = (unsigned int*)(ws + (size_t)4*SLOT);
  unsigned int* hist2 = (unsigned int*)(ws + (size_t)4*SLOT + (1u<<20));
  unsigned int* hist3 = (unsigned int*)(ws + (size_t)4*SLOT + (3u<<20));
  unsigned int* prefs = (unsigned int*)(ws + (size_t)4*SLOT + (4u<<20));
  int*          ranks = (int*)(prefs + 64);

  dim3 blk(64, 4, 1), grd(W_/64, H_/4, B_);

  hmax_kernel<<<B_*H_, 256, 0, stream>>>(Iy, Rh, GBh);
  vscan_fwd_kernel<<<288, 256, 0, stream>>>(Rh, GBh, Rf, Gf);
  vscan_bwd_kernel<<<288, 256, 0, stream>>>(Rh, GBh, Rf, Gf, Iy, xb);
  run_select(xb, vx, 2621, 2622, 259521, 259522, 4, hist1, hist2, hist3, prefs, ranks, stream);
  nhat_gm_kernel<<<grd, blk, 0, stream>>>(xb, vx, nh, Rh /* gm -> slot0 */);
  run_select(Rh, vg, 131071, 131072, 0, 0, 2, hist1, hist2, hist3, prefs, ranks, stream);

  int total = B_*S_;
  init_kernel<<<(total+255)/256, 256, 0, stream>>>(nh, uu[0], ubb[0], pxx[0], pyy[0]);

  dim3 pdg(W_/CORE, H_/CORE, B_);   // 16 x 16 x 16
  int cur = 0;
  int iters[4] = {8, 8, 8, 6};
  for (int L = 0; L < 4; ++L){
    pd_fused_kernel<<<pdg, 256, 0, stream>>>(uu[cur], ubb[cur], pxx[cur], pyy[cur],
                                             uu[1-cur], ubb[1-cur], pxx[1-cur], pyy[1-cur],
                                             nh, vg, iters[L]);
    cur ^= 1;
  }
  // after 4 launches state is back in ping 0 (u = slot1)
  final_kernel<<<(total+255)/256, 256, 0, stream>>>(uu[cur], out);
}

// Round 4
// 699.646 us; speedup vs baseline: 4.2827x; 1.2472x over previous
//
#include <hip/hip_runtime.h>
#include <math.h>

#define B_ 16
#define W_ 512
#define H_ 512
#define S_ (W_*H_)          // 262144 elements per batch image
#define ALPHA_ 0.15f
#define MU_ 10.0f
#define TAU_ 0.125f
#define SIG_ 0.125f
#define EPS_ 1e-6f
#define INV1PT_ (1.0f/(1.0f+TAU_))

// ---- order-preserving float <-> uint key ----
__device__ __forceinline__ unsigned int fkey(float f){
  unsigned int b = __float_as_uint(f);
  return (b & 0x80000000u) ? ~b : (b | 0x80000000u);
}
__device__ __forceinline__ float funkey(unsigned int k){
  unsigned int b = (k & 0x80000000u) ? (k & 0x7fffffffu) : ~k;
  return __uint_as_float(b);
}

// ---- K1: horizontal 31-tap max via log-tree sliding max (1,2,4,8,+15) ----
__global__ __launch_bounds__(256) void hmax_kernel(const float* __restrict__ Iy,
                                                   float* __restrict__ Rh,
                                                   float* __restrict__ GBh){
  __shared__ float bufA[2][544], bufB[2][544];
  int t = threadIdx.x;
  int b = blockIdx.x >> 9;
  int i = blockIdx.x & 511;
  const float* row = Iy + (size_t)b*3*S_ + (size_t)i*W_;
  for (int p = t; p < 544; p += 256){
    int idx = p - 16;
    bool v = (idx >= 0) && (idx < 512);
    bufA[0][p] = v ? row[idx] : -1e30f;
    bufA[1][p] = v ? fmaxf(row[S_+idx], row[2*S_+idx]) : -1e30f;
  }
  __syncthreads();
  float (*src)[544] = bufA; float (*dst)[544] = bufB;
  const int ds[5] = {1, 2, 4, 8, 15};   // windows: 2,4,8,16,31
  #pragma unroll
  for (int sstep = 0; sstep < 5; ++sstep){
    int d = ds[sstep];
    for (int p = t; p < 544; p += 256){
      int q = min(p + d, 543);
      dst[0][p] = fmaxf(src[0][p], src[0][q]);
      dst[1][p] = fmaxf(src[1][p], src[1][q]);
    }
    __syncthreads();
    float (*tmp)[544] = src; src = dst; dst = tmp;
  }
  // out[i] = win31 starting at i-15 -> padded index i+1
  size_t o = (size_t)b*S_ + (size_t)i*W_;
  for (int p = t; p < 512; p += 256){
    Rh[o+p]  = src[0][p+1];
    GBh[o+p] = src[1][p+1];
  }
}

// ---- vertical 31-tap max via van Herk (fwd + bwd scans) ----
__global__ __launch_bounds__(256) void vscan_fwd_kernel(const float* __restrict__ Rh,
                                                        const float* __restrict__ GBh,
                                                        float* __restrict__ Rf,
                                                        float* __restrict__ Gf){
  int gid = blockIdx.x*256 + threadIdx.x;
  int col = gid & 8191;
  int c   = gid >> 13;
  int b = col >> 9, j = col & 511;
  int i0 = c*62, i1 = (c==8) ? 512 : i0+62;
  size_t base = (size_t)b*S_ + j;
  float rR = -1e30f, rG = -1e30f;
  int m = 0;
  for (int i = i0; i < i1; ++i){
    size_t o = base + (size_t)i*W_;
    float vR = Rh[o], vG = GBh[o];
    if (m == 0){ rR = vR; rG = vG; }
    else       { rR = fmaxf(rR, vR); rG = fmaxf(rG, vG); }
    Rf[o] = rR; Gf[o] = rG;
    m = (m==30) ? 0 : m+1;
  }
}

__global__ __launch_bounds__(256) void vscan_bwd_kernel(const float* __restrict__ Rh,
                                                        const float* __restrict__ GBh,
                                                        const float* __restrict__ Rf,
                                                        const float* __restrict__ Gf,
                                                        const float* __restrict__ Iy,
                                                        float* __restrict__ xo){
  int gid = blockIdx.x*256 + threadIdx.x;
  int col = gid & 8191;
  int c   = gid >> 13;
  int b = col >> 9, j = col & 511;
  int i0 = c*62, i1 = (c==8) ? 512 : i0+62;
  size_t base = (size_t)b*S_ + j;
  const float* IyR = Iy + (size_t)b*3*S_ + j;
  float lR = -1e30f, lG = -1e30f;
  int m = (c==8) ? 15 : 30;
  for (int i = i1-1; i >= i0; --i){
    size_t o64 = base + (size_t)i*W_;
    float vR = Rh[o64], vG = GBh[o64];
    if (m == 30){ lR = vR; lG = vG; }
    else        { lR = fmaxf(lR, vR); lG = fmaxf(lG, vG); }
    int o = i + 15;
    if (o < 512){
      int bi = min(i + 30, 511);
      size_t ob = base + (size_t)bi*W_;
      float mR = fmaxf(lR, Rf[ob]);
      float mG = fmaxf(lG, Gf[ob]);
      xo[base + (size_t)o*W_] = fabsf(mR - mG) + IyR[(size_t)o*W_];
    }
    m = (m==0) ? 30 : m-1;
  }
  if (c == 0){
    for (int o = 0; o < 15; ++o){
      size_t ob = base + (size_t)(o+15)*W_;
      float mR = Rf[ob], mG = Gf[ob];
      xo[base + (size_t)o*W_] = fabsf(mR - mG) + IyR[(size_t)o*W_];
    }
  }
}

// ================= grid-parallel exact radix select =================
__global__ __launch_bounds__(256) void hist12_kernel(const float* __restrict__ data,
                                                     unsigned int* __restrict__ hist,
                                                     int blocks_per_batch){
  __shared__ unsigned int h[4096];
  int b   = blockIdx.x / blocks_per_batch;
  int blk = blockIdx.x - b*blocks_per_batch;
  for (int t = threadIdx.x; t < 4096; t += 256) h[t] = 0u;
  __syncthreads();
  int chunk = S_ / blocks_per_batch;
  const float* p = data + (size_t)b*S_ + (size_t)blk*chunk;
  for (int idx = threadIdx.x; idx < chunk; idx += 256){
    unsigned int key = fkey(p[idx]);
    atomicAdd(&h[key >> 20], 1u);
  }
  __syncthreads();
  for (int t = threadIdx.x; t < 4096; t += 256)
    if (h[t]) atomicAdd(&hist[b*4096 + t], h[t]);
}

__global__ __launch_bounds__(256) void hist_refine_kernel(const float* __restrict__ data,
                                                          const unsigned int* __restrict__ prefs,
                                                          unsigned int* __restrict__ hist,
                                                          int blocks_per_job, int nranks,
                                                          int fshift, int bshift, int nbins){
  __shared__ unsigned int h[4096];
  int job = blockIdx.x / blocks_per_job;
  int blk = blockIdx.x - job*blocks_per_job;
  int b = job / nranks;
  unsigned int pref = prefs[job];
  for (int t = threadIdx.x; t < nbins; t += 256) h[t] = 0u;
  __syncthreads();
  int chunk = S_ / blocks_per_job;
  const float* p = data + (size_t)b*S_ + (size_t)blk*chunk;
  for (int idx = threadIdx.x; idx < chunk; idx += 256){
    unsigned int key = fkey(p[idx]);
    if ((key >> fshift) == pref) atomicAdd(&h[(key >> bshift) & (unsigned)(nbins-1)], 1u);
  }
  __syncthreads();
  for (int t = threadIdx.x; t < nbins; t += 256)
    if (h[t]) atomicAdd(&hist[job*nbins + t], h[t]);
}

__global__ __launch_bounds__(256) void pick12_kernel(const unsigned int* __restrict__ hist,
                                                     unsigned int* __restrict__ prefs,
                                                     int* __restrict__ ranks,
                                                     int r0, int r1, int r2, int r3,
                                                     int nranks, int first){
  __shared__ unsigned int part[256];
  __shared__ int s_owner, s_rem;
  int job = blockIdx.x;
  int b = job / nranks, ri = job - b*nranks;
  int rank; int base; unsigned int oldpref = 0u;
  if (first){
    rank = (ri==0) ? r0 : (ri==1) ? r1 : (ri==2) ? r2 : r3;
    base = b*4096;
  } else {
    rank = ranks[job];
    base = job*4096;
    oldpref = prefs[job];
  }
  int t = threadIdx.x;
  unsigned int local[16];
  unsigned int cnt = 0u;
  #pragma unroll
  for (int q = 0; q < 16; ++q){ local[q] = hist[base + t*16 + q]; cnt += local[q]; }
  part[t] = cnt;
  __syncthreads();
  if (t == 0){
    int rem = rank; int owner = 255;
    for (int q = 0; q < 256; ++q){
      if ((unsigned int)rem < part[q]){ owner = q; break; }
      rem -= (int)part[q];
    }
    s_owner = owner; s_rem = rem;
  }
  __syncthreads();
  if (t == s_owner){
    int rem = s_rem; unsigned int bin = (unsigned int)(t*16 + 15);
    #pragma unroll
    for (int q = 0; q < 16; ++q){
      if ((unsigned int)rem < local[q]){ bin = (unsigned int)(t*16 + q); break; }
      rem -= (int)local[q];
    }
    prefs[job] = first ? bin : ((oldpref << 12) | bin);
    ranks[job] = rem;
  }
}

__global__ __launch_bounds__(256) void pick3_kernel(const unsigned int* __restrict__ hist3,
                                                    const unsigned int* __restrict__ prefs,
                                                    const int* __restrict__ ranks,
                                                    float* __restrict__ outv,
                                                    int nranks){
  __shared__ unsigned int part[256];
  int job = blockIdx.x;
  part[threadIdx.x] = hist3[job*256 + threadIdx.x];
  __syncthreads();
  if (threadIdx.x == 0){
    int rem = ranks[job]; unsigned int bin = 255u;
    for (int q = 0; q < 256; ++q){
      if ((unsigned int)rem < part[q]){ bin = (unsigned int)q; break; }
      rem -= (int)part[q];
    }
    unsigned int key = (prefs[job] << 8) | bin;
    outv[job] = funkey(key);
  }
}

// ---- N_hat + grad_mag ----
__global__ __launch_bounds__(256) void nhat_gm_kernel(const float* __restrict__ x,
                                                      const float* __restrict__ vx,
                                                      float* __restrict__ nh,
                                                      float* __restrict__ gm){
  int j = blockIdx.x*64 + threadIdx.x;
  int i = blockIdx.y*4 + threadIdx.y;
  int b = blockIdx.z;
  float lo = vx[b*4+0]*(1.0f-0.43f) + vx[b*4+1]*0.43f;
  float hi = vx[b*4+2]*(1.0f-0.57f) + vx[b*4+3]*0.57f;
  float inv = 1.0f/(hi - lo + EPS_);
  size_t base = (size_t)b*S_ + (size_t)i*W_ + j;
  float c = fminf(fmaxf((x[base] - lo)*inv, 0.f), 1.f);
  float dx = 0.f, dy = 0.f;
  if (j < W_-1) dx = fminf(fmaxf((x[base+1]  - lo)*inv, 0.f), 1.f) - c;
  if (i < H_-1) dy = fminf(fmaxf((x[base+W_] - lo)*inv, 0.f), 1.f) - c;
  nh[base] = c;
  gm[base] = sqrtf(dx*dx + dy*dy + EPS_);
}

// ---- fused T-iteration primal-dual, 3x3 patch per thread ----
// Tile 48x48 = 16x16 patches; core 32x32, halo 8. Interior neighbor accesses
// come from registers; only patch-boundary values cross LDS (12R + 11W per
// thread-iter vs 63 in the px-per-thread layout). px,py are never STAGED in
// LDS: boundary cells are always written (dual step) before read (primal).
// Image edges: px,py == 0 identically at right/bottom edge -> clamp bound 0;
// left/top divergence terms masked by mL/mU in {0,1} (fma).
#define TILE 48
#define NPIX (TILE*TILE)
#define CORE 32
#define HALO 8

__global__ __launch_bounds__(256, 4) void pd_fused_kernel(
    const float* __restrict__ u_in,  const float* __restrict__ ub_in,
    const float* __restrict__ px_in, const float* __restrict__ py_in,
    float* __restrict__ u_out,  float* __restrict__ ub_out,
    float* __restrict__ px_out, float* __restrict__ py_out,
    const float* __restrict__ nh_g, const float* __restrict__ vg,
    int T, int mode)   // mode 1 = first launch (init from nh), 2 = last (store u only)
{
  __shared__ float ubS[NPIX], pxS[NPIX], pyS[NPIX];
  const int t = threadIdx.x;
  const int b = blockIdx.z;
  const int gi0 = blockIdx.y*CORE - HALO;
  const int gj0 = blockIdx.x*CORE - HALO;
  const float sig = fmaxf(0.5f*(vg[2*b] + vg[2*b+1]), EPS_);
  const float invs = 1.0f/sig;
  const int pi = t >> 4, pj = t & 15;
  const int r0 = 3*pi, c0 = 3*pj;
  const size_t bb = (size_t)b*S_;

  // ---- linear coalesced staging (clamped coords) ----
  float* nhStage = (mode==1) ? ubS : pyS;
  #pragma unroll
  for (int k = 0; k < 9; ++k){
    int p = t + k*256;
    int li = p/TILE, lj = p - li*TILE;
    int gi = min(max(gi0+li,0),H_-1), gj = min(max(gj0+lj,0),W_-1);
    size_t g = bb + (size_t)gi*W_ + gj;
    nhStage[p] = nh_g[g];
    if (mode != 1) ubS[p] = ub_in[g];
    pxS[p] = 0.f;                       // defined values for clamped edge reads
    if (mode == 1) pyS[p] = 0.f;
  }
  __syncthreads();

  float nh_r[9], ax[9], ay[9], mL[9], mU[9];
  float u_r[9], ub_r[9], px_r[9], py_r[9];
  #pragma unroll
  for (int r = 0; r < 3; ++r)
  #pragma unroll
  for (int c = 0; c < 3; ++c){
    const int q = r*3+c;
    const int li = r0+r, lj = c0+c;
    const int gi = gi0+li, gj = gj0+lj;
    float nhc = nhStage[li*TILE+lj];
    float nhR = nhStage[li*TILE + min(lj+1,TILE-1)];
    float nhD = nhStage[min(li+1,TILE-1)*TILE + lj];
    nh_r[q] = nhc;
    ax[q] = (gj < W_-1) ? ALPHA_*(1.f + MU_*__expf(-fabsf(nhR-nhc)*invs)) : 0.f;
    ay[q] = (gi < H_-1) ? ALPHA_*(1.f + MU_*__expf(-fabsf(nhD-nhc)*invs)) : 0.f;
    mL[q] = (gj > 0) ? 1.f : 0.f;
    mU[q] = (gi > 0) ? 1.f : 0.f;
    if (mode == 1){
      u_r[q] = nhc; ub_r[q] = nhc; px_r[q] = 0.f; py_r[q] = 0.f;
    } else {
      int gic = min(max(gi,0),H_-1), gjc = min(max(gj,0),W_-1);
      size_t g = bb + (size_t)gic*W_ + gjc;
      u_r[q]  = u_in[g];
      ub_r[q] = ubS[li*TILE+lj];
      px_r[q] = px_in[g];
      py_r[q] = py_in[g];
    }
  }
  __syncthreads();   // staging reads done before iter-loop LDS writes

  for (int s = 0; s < T; ++s){
    // ---- dual update (px, py) ----
    float ubR_col[3], ubD_row[3];
    ubR_col[0] = ubS[(r0+0)*TILE + min(c0+3,TILE-1)];
    ubR_col[1] = ubS[(r0+1)*TILE + min(c0+3,TILE-1)];
    ubR_col[2] = ubS[(r0+2)*TILE + min(c0+3,TILE-1)];
    ubD_row[0] = ubS[min(r0+3,TILE-1)*TILE + c0+0];
    ubD_row[1] = ubS[min(r0+3,TILE-1)*TILE + c0+1];
    ubD_row[2] = ubS[min(r0+3,TILE-1)*TILE + c0+2];
    #pragma unroll
    for (int r = 0; r < 3; ++r)
    #pragma unroll
    for (int c = 0; c < 3; ++c){
      const int q = r*3+c;
      float ubR = (c < 2) ? ub_r[q+1] : ubR_col[r];
      float ubD = (r < 2) ? ub_r[q+3] : ubD_row[c];
      px_r[q] = fminf(fmaxf(fmaf(SIG_, ubR - ub_r[q], px_r[q]), -ax[q]), ax[q]);
      py_r[q] = fminf(fmaxf(fmaf(SIG_, ubD - ub_r[q], py_r[q]), -ay[q]), ay[q]);
    }
    pxS[(r0+0)*TILE + c0+2] = px_r[2];
    pxS[(r0+1)*TILE + c0+2] = px_r[5];
    pxS[(r0+2)*TILE + c0+2] = px_r[8];
    pyS[(r0+2)*TILE + c0+0] = py_r[6];
    pyS[(r0+2)*TILE + c0+1] = py_r[7];
    pyS[(r0+2)*TILE + c0+2] = py_r[8];
    __syncthreads();
    // ---- primal update (u, ub) ----
    float pxL_col[3], pyU_row[3];
    pxL_col[0] = pxS[(r0+0)*TILE + max(c0-1,0)];
    pxL_col[1] = pxS[(r0+1)*TILE + max(c0-1,0)];
    pxL_col[2] = pxS[(r0+2)*TILE + max(c0-1,0)];
    pyU_row[0] = pyS[max(r0-1,0)*TILE + c0+0];
    pyU_row[1] = pyS[max(r0-1,0)*TILE + c0+1];
    pyU_row[2] = pyS[max(r0-1,0)*TILE + c0+2];
    #pragma unroll
    for (int r = 0; r < 3; ++r)
    #pragma unroll
    for (int c = 0; c < 3; ++c){
      const int q = r*3+c;
      float pxL = (c > 0) ? px_r[q-1] : pxL_col[r];
      float pyU = (r > 0) ? py_r[q-3] : pyU_row[c];
      float div = px_r[q] + py_r[q] - mL[q]*pxL - mU[q]*pyU;
      float un = fmaf(TAU_, div + nh_r[q], u_r[q]) * INV1PT_;
      ub_r[q] = 2.f*un - u_r[q];
      u_r[q] = un;
    }
    ubS[(r0+0)*TILE + c0]   = ub_r[0];
    ubS[(r0+1)*TILE + c0]   = ub_r[3];
    ubS[(r0+2)*TILE + c0]   = ub_r[6];
    ubS[r0*TILE + c0+1]     = ub_r[1];
    ubS[r0*TILE + c0+2]     = ub_r[2];
    __syncthreads();
  }

  // ---- write back core pixels ----
  #pragma unroll
  for (int r = 0; r < 3; ++r)
  #pragma unroll
  for (int c = 0; c < 3; ++c){
    const int q = r*3+c;
    const int li = r0+r, lj = c0+c;
    if (li >= HALO && li < HALO+CORE && lj >= HALO && lj < HALO+CORE){
      size_t g = bb + (size_t)(gi0+li)*W_ + (gj0+lj);
      u_out[g] = u_r[q];
      if (mode != 2){
        ub_out[g] = ub_r[q];
        px_out[g] = px_r[q];
        py_out[g] = py_r[q];
      }
    }
  }
}

// ---- final clip ----
__global__ __launch_bounds__(256) void final_kernel(const float* __restrict__ u,
                                                    float* __restrict__ out){
  size_t idx = (size_t)blockIdx.x*256 + threadIdx.x;
  if (idx < (size_t)B_*S_) out[idx] = fminf(fmaxf(u[idx], 0.f), 1.f);
}

static void run_select(const float* data, float* outv,
                       int r0, int r1, int r2, int r3, int nranks,
                       unsigned int* hist1, unsigned int* hist2, unsigned int* hist3,
                       unsigned int* prefs, int* ranks, hipStream_t stream){
  int jobs = B_ * nranks;
  // hist1/2/3 contiguous, zeroed by caller in one memset
  hist12_kernel<<<B_*16, 256, 0, stream>>>(data, hist1, 16);
  pick12_kernel<<<jobs, 256, 0, stream>>>(hist1, prefs, ranks, r0, r1, r2, r3, nranks, 1);
  hist_refine_kernel<<<jobs*8, 256, 0, stream>>>(data, prefs, hist2, 8, nranks, 20, 8, 4096);
  pick12_kernel<<<jobs, 256, 0, stream>>>(hist2, prefs, ranks, 0, 0, 0, 0, nranks, 0);
  hist_refine_kernel<<<jobs*8, 256, 0, stream>>>(data, prefs, hist3, 8, nranks, 8, 0, 256);
  pick3_kernel<<<jobs, 256, 0, stream>>>(hist3, prefs, ranks, outv, nranks);
}

extern "C" void kernel_launch(void* const* d_in, const int* in_sizes, int n_in,
                              void* d_out, int out_size, void* d_ws, size_t ws_size,
                              hipStream_t stream){
  const float* Iy = (const float*)d_in[0];
  float* out = (float*)d_out;
  char* ws = (char*)d_ws;
  const size_t SLOT = (size_t)B_*S_*sizeof(float);   // 16 MiB per field
  float* slot[8];
  for (int q = 0; q < 8; ++q) slot[q] = (float*)(ws + (size_t)q*SLOT);
  float* vx = (float*)(ws + (size_t)8*SLOT);          // 64 floats
  float* vg = vx + 64;                                // 32 floats

  // Slot lifetimes:
  // s0: Rh -> gm -> py ping B        s1: GBh -> u ping A
  // s2: x -> ub ping A               s3: px ping A
  // s4: select hists -> py ping A    s5: Rf -> u ping B
  // s6: Gf -> ub ping B              s7: px ping B
  // nh lives in d_out (overwritten only by final_kernel).
  float* Rh  = slot[0];
  float* GBh = slot[1];
  float* Rf  = slot[5];
  float* Gf  = slot[6];
  float* xb  = slot[2];
  float* nh  = out;
  float* uu[2]   = { slot[1], slot[5] };
  float* ubb[2]  = { slot[2], slot[6] };
  float* pxx[2]  = { slot[3], slot[7] };
  float* pyy[2]  = { slot[4], slot[0] };

  // contiguous select scratch inside slot4 (dead before PD writes it)
  unsigned int* hist1 = (unsigned int*)(ws + (size_t)4*SLOT);            // 256 KiB
  unsigned int* hist2 = hist1 + 4096*B_;                                 // 1 MiB
  unsigned int* hist3 = hist2 + 4096*B_*4;                               // 64 KiB
  unsigned int* prefs = hist3 + 256*B_*4;                                // 64 u32
  int*          ranks = (int*)(prefs + 64);
  const size_t HISTBYTES = (size_t)(4096*B_ + 4096*B_*4 + 256*B_*4 + 128)*4;

  dim3 blk(64, 4, 1), grd(W_/64, H_/4, B_);

  hmax_kernel<<<B_*H_, 256, 0, stream>>>(Iy, Rh, GBh);
  vscan_fwd_kernel<<<288, 256, 0, stream>>>(Rh, GBh, Rf, Gf);
  vscan_bwd_kernel<<<288, 256, 0, stream>>>(Rh, GBh, Rf, Gf, Iy, xb);
  hipMemsetAsync(hist1, 0, HISTBYTES, stream);
  run_select(xb, vx, 2621, 2622, 259521, 259522, 4, hist1, hist2, hist3, prefs, ranks, stream);
  nhat_gm_kernel<<<grd, blk, 0, stream>>>(xb, vx, nh, Rh /* gm -> slot0 */);
  hipMemsetAsync(hist1, 0, HISTBYTES, stream);
  run_select(Rh, vg, 131071, 131072, 0, 0, 2, hist1, hist2, hist3, prefs, ranks, stream);

  dim3 pdg(W_/CORE, H_/CORE, B_);   // 16 x 16 x 16
  // L0: init from nh -> ping0 ; L1: ping0 -> ping1 ; L2: ping1 -> ping0 ;
  // L3: ping0 -> ping1 (u only)
  pd_fused_kernel<<<pdg, 256, 0, stream>>>(nh, nh, nh, nh,
                                           uu[0], ubb[0], pxx[0], pyy[0],
                                           nh, vg, 8, 1);
  pd_fused_kernel<<<pdg, 256, 0, stream>>>(uu[0], ubb[0], pxx[0], pyy[0],
                                           uu[1], ubb[1], pxx[1], pyy[1],
                                           nh, vg, 8, 0);
  pd_fused_kernel<<<pdg, 256, 0, stream>>>(uu[1], ubb[1], pxx[1], pyy[1],
                                           uu[0], ubb[0], pxx[0], pyy[0],
                                           nh, vg, 8, 0);
  pd_fused_kernel<<<pdg, 256, 0, stream>>>(uu[0], ubb[0], pxx[0], pyy[0],
                                           uu[1], ubb[1], pxx[1], pyy[1],
                                           nh, vg, 6, 2);

  int total = B_*S_;
  final_kernel<<<(total+255)/256, 256, 0, stream>>>(uu[1], out);
}